// Round 14
// baseline (301.400 us; speedup 1.0000x reference)
//
#include <hip/hip_runtime.h>
#include <math.h>

#define D      256
#define NTOK   4096
#define BATCH  2
#define NBC    4          // BATCH * 2 branches
#define NSPLIT 4          // m-reduction splits for AV
#define EPS    1e-8f
#define SCALE  0.0625f    // 256^-0.5

// NOTE: Pbuf and yTb store the m-dimension PERMUTED within each 64-block:
// orig within-block col c -> stored pos p(c) = 4*(c%16) + (c/16).
// Legal because m is only ever (a) contracted P.y over m with BOTH sides
// permuted identically, (b) summed (Zq, entropy), (c) grouped by ay=m>>6
// which is constant within a 64-block. Enables 8B packed epilogue stores.

typedef unsigned short ushortt;
typedef __attribute__((ext_vector_type(8))) short   bf16x8;
typedef __attribute__((ext_vector_type(4))) float   f32x4;
typedef __attribute__((ext_vector_type(4))) unsigned short u16x4;
typedef __attribute__((ext_vector_type(8))) unsigned short u16x8;
typedef unsigned int u32;

__device__ __forceinline__ ushortt f2bf(float f) {
    u32 u = __builtin_bit_cast(u32, f);
    u += 0x7FFFu + ((u >> 16) & 1u);      // round-to-nearest-even
    return (ushortt)(u >> 16);
}
__device__ __forceinline__ float bf2f(ushortt h) {
    u32 u = ((u32)h) << 16;
    return __builtin_bit_cast(float, u);
}

__device__ __forceinline__ void gload16(const ushortt* g, short* l) {
    __builtin_amdgcn_global_load_lds(
        (const __attribute__((address_space(1))) u32*)(const void*)g,
        (__attribute__((address_space(3))) u32*)(void*)l, 16, 0, 0);
}

// ---------------------------------------------------------------------------
// MFMA NT-GEMM core: C[128x128] = A[128xK] * B^T, row-major, K inner.
// 4 waves (2x2), per-wave 64x64 = 4x4 frags. LDS 2x16KB, XOR-swizzled.
// ---------------------------------------------------------------------------
__device__ __forceinline__ void mm_core(
    const ushortt* __restrict__ Ag, int lda,
    const ushortt* __restrict__ Bg, int ldb,
    int K, short* As, short* Bs, f32x4 acc[4][4])
{
    const int t = threadIdx.x, lane = t & 63, w = t >> 6;
    const int wr = w >> 1, wc = w & 1;
    const int l15 = lane & 15, l4 = lane >> 4;

    for (int k0 = 0; k0 < K; k0 += 64) {
        __syncthreads();
#pragma unroll
        for (int q = 0; q < 4; ++q) {
            int slot = (w * 4 + q) * 64 + lane;     // granule slot [0,1024)
            int r    = slot >> 3;
            int kgp  = slot & 7;
            int kg   = kgp ^ (r & 7);               // involution
            gload16(Ag + (size_t)r * lda + k0 + kg * 8, As + (w * 4 + q) * 512);
            gload16(Bg + (size_t)r * ldb + k0 + kg * 8, Bs + (w * 4 + q) * 512);
        }
        asm volatile("s_waitcnt vmcnt(0)" ::: "memory");
        __syncthreads();
#pragma unroll
        for (int kk = 0; kk < 2; ++kk) {
            bf16x8 af[4], bfr[4];
#pragma unroll
            for (int i = 0; i < 4; ++i) {
                int r  = wr * 64 + i * 16 + l15;
                int kg = kk * 4 + l4;
                af[i] = *(const bf16x8*)&As[(r * 8 + (kg ^ (r & 7))) * 8];
            }
#pragma unroll
            for (int j = 0; j < 4; ++j) {
                int c  = wc * 64 + j * 16 + l15;
                int kg = kk * 4 + l4;
                bfr[j] = *(const bf16x8*)&Bs[(c * 8 + (kg ^ (c & 7))) * 8];
            }
#pragma unroll
            for (int i = 0; i < 4; ++i)
#pragma unroll
                for (int j = 0; j < 4; ++j)
                    acc[i][j] = __builtin_amdgcn_mfma_f32_16x16x32_bf16(
                        af[i], bfr[j], acc[i][j], 0, 0, 0);
        }
    }
}

// ---------------------------------------------------------------------------
// K0: M2_bf[c][i][j] = bf16( sum_k U[k][i]*Sc[k]^2*U[k][j] )
// ---------------------------------------------------------------------------
__global__ __launch_bounds__(256)
void k_prepM(const float* __restrict__ U, const float* __restrict__ S1,
             const float* __restrict__ S2, ushortt* __restrict__ M2b) {
    int idx = blockIdx.x * 256 + threadIdx.x;
    int c  = idx >> 16;
    int ij = idx & 65535;
    int i = ij >> 8, j = ij & 255;
    const float* S = c ? S2 : S1;
    float acc = 0.f;
    for (int k = 0; k < D; ++k) {
        float s = S[k];
        acc += U[k * D + i] * U[k * D + j] * (s * s);
    }
    M2b[idx] = f2bf(acc);
}

// ---------------------------------------------------------------------------
// x,y -> bf16
// ---------------------------------------------------------------------------
__global__ __launch_bounds__(256)
void k_cast(const float* __restrict__ x, const float* __restrict__ y,
            ushortt* __restrict__ xb, ushortt* __restrict__ yb) {
    int i = (blockIdx.x * 256 + threadIdx.x) * 4;
    float4 vx = *(const float4*)&x[i];
    float4 vy = *(const float4*)&y[i];
    u16x4 ox = { f2bf(vx.x), f2bf(vx.y), f2bf(vx.z), f2bf(vx.w) };
    u16x4 oy = { f2bf(vy.x), f2bf(vy.y), f2bf(vy.z), f2bf(vy.w) };
    *(u16x4*)&xb[i] = ox;
    *(u16x4*)&yb[i] = oy;
}

// ---------------------------------------------------------------------------
// y [b][m][d] -> yT_bf [b][d][pi(m)]  (m permuted within 64-blocks: matches
// the qkexp P-store layout: stored p = 4k+j holds orig m = m0 + k + 16*j)
// ---------------------------------------------------------------------------
__global__ __launch_bounds__(256)
void k_transT(const float* __restrict__ y, ushortt* __restrict__ yT) {
    __shared__ float tile[64][65];
    const int b = blockIdx.z, d0 = blockIdx.y * 64, m0 = blockIdx.x * 64;
    const int t = threadIdx.x;
    const int c4 = (t & 15) * 4, r = t >> 4;
#pragma unroll
    for (int rr = r; rr < 64; rr += 16) {
        float4 v = *(const float4*)&y[((size_t)b * NTOK + m0 + rr) * D + d0 + c4];
        tile[rr][c4 + 0] = v.x; tile[rr][c4 + 1] = v.y;
        tile[rr][c4 + 2] = v.z; tile[rr][c4 + 3] = v.w;
    }
    __syncthreads();
    const int k = t & 15;
#pragma unroll
    for (int dd = t >> 4; dd < 64; dd += 16) {
        u16x4 o = { f2bf(tile[k +  0][dd]), f2bf(tile[k + 16][dd]),
                    f2bf(tile[k + 32][dd]), f2bf(tile[k + 48][dd]) };
        *(u16x4*)&yT[((size_t)b * D + d0 + dd) * NTOK + m0 + k * 4] = o;
    }
}

// ---------------------------------------------------------------------------
// Ysum[b][ay][d] = sum_{w<64} y[b][ay*64+w][d]   (fp32)
// ---------------------------------------------------------------------------
__global__ __launch_bounds__(256)
void k_ysum(const float* __restrict__ y, float* __restrict__ Ysum) {
    const int blk = blockIdx.x;          // b*64 + ay
    const int b = blk >> 6, ay = blk & 63;
    const int d = threadIdx.x;
    float acc = 0.f;
    const float* base = y + ((size_t)b * NTOK + ay * 64) * D + d;
#pragma unroll 8
    for (int w = 0; w < 64; ++w) acc += base[w * D];
    Ysum[(size_t)blk * D + d] = acc;
}

// ---------------------------------------------------------------------------
// posY[b][ayq][d] = sum_aym e(aym)*Ysum[b][aym][d] / (64*sum_aym e(aym))
// ---------------------------------------------------------------------------
__global__ __launch_bounds__(256)
void k_posY(const float* __restrict__ Ysum, const float* __restrict__ focusp,
            float* __restrict__ posY) {
    __shared__ float e[64];
    const int blk = blockIdx.x;          // b*64 + ayq
    const int b = blk >> 6, ayq = blk & 63;
    const int t = threadIdx.x;
    const float f = fabsf(focusp[0]);
    if (t < 64) { float dy = (float)(t - ayq); e[t] = __expf(-f * dy * dy); }
    __syncthreads();
    float zs = 0.f;
#pragma unroll
    for (int j = 0; j < 64; ++j) zs += e[j];
    const float winv = 1.f / (64.f * zs);
    float acc = 0.f;
    const float* Yb = Ysum + (size_t)b * 64 * D + t;
#pragma unroll 8
    for (int aym = 0; aym < 64; ++aym) acc += e[aym] * Yb[aym * D];
    posY[(size_t)blk * D + t] = acc * winv;
}

// ---------------------------------------------------------------------------
// xs_bf[bc][n][d] = bf16( x_bf[b][n][:] . M2_bf[c][d][:] )
// ---------------------------------------------------------------------------
__global__ __launch_bounds__(256)
void k_xs_mm(const ushortt* __restrict__ xb, const ushortt* __restrict__ M2b,
             ushortt* __restrict__ xsb) {
    __shared__ __align__(16) short As[8192];
    __shared__ __align__(16) short Bs[8192];
    const int bc = blockIdx.z, b = bc >> 1, c = bc & 1;
    const int d0 = blockIdx.x * 128, n0 = blockIdx.y * 128;
    f32x4 z = {0.f, 0.f, 0.f, 0.f};
    f32x4 acc[4][4];
#pragma unroll
    for (int i = 0; i < 4; ++i)
#pragma unroll
        for (int j = 0; j < 4; ++j) acc[i][j] = z;

    mm_core(xb + ((size_t)b * NTOK + n0) * D, D,
            M2b + (size_t)c * D * D + (size_t)d0 * D, D,
            D, As, Bs, acc);

    const int t = threadIdx.x, lane = t & 63, w = t >> 6;
    const int wr = w >> 1, wc = w & 1, l15 = lane & 15, l4 = lane >> 4;
#pragma unroll
    for (int i = 0; i < 4; ++i)
#pragma unroll
        for (int e = 0; e < 4; ++e) {
            int n = n0 + wr * 64 + i * 16 + l4 * 4 + e;
            ushortt* p = xsb + ((size_t)bc * NTOK + n) * D + d0 + wc * 64;
#pragma unroll
            for (int j = 0; j < 4; ++j) p[j * 16 + l15] = f2bf(acc[i][j][e]);
        }
}

// ---------------------------------------------------------------------------
// QK + exp: Pbuf[bc][n][pi(m)] = bf16(exp(SCALE * xs.y)) with packed 8B
// stores (lane's 4 frag values -> contiguous stored pos l15*4+j).
// Per-(mtile,wave) row sums -> Zqp[64 planes][bc][n].
// ---------------------------------------------------------------------------
__global__ __launch_bounds__(256)
void k_qkexp(const ushortt* __restrict__ xsb, const ushortt* __restrict__ yb,
             ushortt* __restrict__ Pbuf, float* __restrict__ Zqp) {
    __shared__ __align__(16) short As[8192];
    __shared__ __align__(16) short Bs[8192];
    const int bc = blockIdx.z, b = bc >> 1;
    const int m0 = blockIdx.x * 128, n0 = blockIdx.y * 128;
    f32x4 z = {0.f, 0.f, 0.f, 0.f};
    f32x4 acc[4][4];
#pragma unroll
    for (int i = 0; i < 4; ++i)
#pragma unroll
        for (int j = 0; j < 4; ++j) acc[i][j] = z;

    mm_core(xsb + ((size_t)bc * NTOK + n0) * D, D,
            yb + ((size_t)b * NTOK + m0) * D, D,
            D, As, Bs, acc);

    const int t = threadIdx.x, lane = t & 63, w = t >> 6;
    const int wr = w >> 1, wc = w & 1, l15 = lane & 15, l4 = lane >> 4;
    const int plane = (m0 >> 7) * 2 + wc;          // 64 planes
#pragma unroll
    for (int i = 0; i < 4; ++i)
#pragma unroll
        for (int e = 0; e < 4; ++e) {
            int n = n0 + wr * 64 + i * 16 + l4 * 4 + e;
            ushortt* Prow = Pbuf + ((size_t)bc * NTOK + n) * NTOK + m0 + wc * 64;
            float p0 = __expf(acc[i][0][e] * SCALE);
            float p1 = __expf(acc[i][1][e] * SCALE);
            float p2 = __expf(acc[i][2][e] * SCALE);
            float p3 = __expf(acc[i][3][e] * SCALE);
            u16x4 P4 = { f2bf(p0), f2bf(p1), f2bf(p2), f2bf(p3) };
            *(u16x4*)&Prow[l15 * 4] = P4;          // permuted-contiguous
            float rsum = (p0 + p1) + (p2 + p3);
            rsum += __shfl_xor(rsum, 1);
            rsum += __shfl_xor(rsum, 2);
            rsum += __shfl_xor(rsum, 4);
            rsum += __shfl_xor(rsum, 8);
            if (l15 == 0)
                Zqp[((size_t)plane * NBC + bc) * NTOK + n] = rsum;
        }
}

// ---------------------------------------------------------------------------
// Zq[bc][n] = sum_{p<64} Zqp[p][bc][n]
// ---------------------------------------------------------------------------
__global__ __launch_bounds__(256)
void k_zqred(const float* __restrict__ Zqp, float* __restrict__ Zq) {
    int id = blockIdx.x * 256 + threadIdx.x;       // [0, NBC*NTOK)
    float s = 0.f;
#pragma unroll 8
    for (int p = 0; p < 64; ++p) s += Zqp[(size_t)p * NBC * NTOK + id];
    Zq[id] = s;
}

// ---------------------------------------------------------------------------
// Entropy pass: contiguous 16 elems/thread, 2x16B loads. ay uniform per thread.
// ---------------------------------------------------------------------------
__device__ inline float blockSum(float v, volatile float* red) {
#pragma unroll
    for (int o = 32; o; o >>= 1) v += __shfl_down(v, o);
    int lane = threadIdx.x & 63, wid = threadIdx.x >> 6;
    if (lane == 0) red[wid] = v;
    __syncthreads();
    float r = red[0] + red[1] + red[2] + red[3];
    __syncthreads();
    return r;
}

__global__ __launch_bounds__(256)
void k_ent(const ushortt* __restrict__ Pbuf, const float* __restrict__ Zq,
           const float* __restrict__ focusp, const float* __restrict__ gatingp,
           float* __restrict__ ent, float* __restrict__ srw) {
    __shared__ float red[4];
    __shared__ float zparr[64];
    const int t = threadIdx.x;
    const int n = blockIdx.x, bc = blockIdx.y;
    const ushortt* Prow = Pbuf + ((size_t)bc * NTOK + n) * NTOK;

    const float f  = fabsf(focusp[0]);
    const float g  = 1.f / (1.f + __expf(-gatingp[0]));
    const float cg = 1.f - g;

    int ayn = n >> 6;
    if (t < 64) { float dy = (float)(t - ayn); zparr[t] = __expf(-f * dy * dy); }
    __syncthreads();
    float zp = 0.f;
#pragma unroll
    for (int j = 0; j < 64; ++j) zp += zparr[j];
    const float wq = cg / Zq[bc * NTOK + n];
    const float wp = g / (64.f * zp);
    const float pw = zparr[t >> 2] * wp;          // ay = (t*16)>>6 = t>>2

    u16x8 h0 = *(const u16x8*)&Prow[t * 16];
    u16x8 h1 = *(const u16x8*)&Prow[t * 16 + 8];
    float v[16];
#pragma unroll
    for (int i = 0; i < 8; ++i) v[i]     = bf2f(h0[i]) * wq + pw;
#pragma unroll
    for (int i = 0; i < 8; ++i) v[8 + i] = bf2f(h1[i]) * wq + pw;

    float ss = 0.f;
#pragma unroll
    for (int i = 0; i < 16; ++i) ss += v[i];
    float Srw = blockSum(ss, red);
    float inv = 1.f / Srw;
    float hp = 0.f;
#pragma unroll
    for (int i = 0; i < 16; ++i) {
        float a = v[i] * inv;
        hp -= a * __logf(a + EPS);
    }
    float H = blockSum(hp, red);
    if (t == 0) {
        ent[bc * NTOK + n] = H;
        srw[bc * NTOK + n] = Srw;
    }
}

// ---------------------------------------------------------------------------
// Routing + heat output
// ---------------------------------------------------------------------------
__global__ __launch_bounds__(256)
void k_route(const float* __restrict__ ent, const float* __restrict__ tempp,
             float* __restrict__ fsel, float* __restrict__ out) {
    int idx = blockIdx.x * 256 + threadIdx.x;     // [0, BATCH*NTOK)
    if (idx >= BATCH * NTOK) return;
    int b = idx >> 12, n = idx & 4095;
    float tp = tempp[0];
    float H0 = ent[(b * 2 + 0) * NTOK + n];
    float H1 = ent[(b * 2 + 1) * NTOK + n];
    float hm0 = 2.f - 2.f / (1.f + __expf(-tp * H0));
    float hm1 = 2.f - 2.f / (1.f + __expf(-tp * H1));
    int sel = (hm0 >= hm1) ? 0 : 1;
    fsel[idx] = (float)sel;
    out[(size_t)BATCH * NTOK * D + idx] = sel ? hm1 : hm0;
}

// ---------------------------------------------------------------------------
// AV partial: Opart[s][b][n][d] = sum_{m in split s} P[bc][n][m]*y[b][m][d]
// (both operands in the SAME permuted m-layout -> dot product invariant)
// ---------------------------------------------------------------------------
__global__ __launch_bounds__(256)
void k_av_mm(const ushortt* __restrict__ Pbuf, const ushortt* __restrict__ yTb,
             const float* __restrict__ fsel, float* __restrict__ Opart) {
    __shared__ __align__(16) short As[8192];
    __shared__ __align__(16) short Bs[8192];
    __shared__ int any;
    const int zz = blockIdx.z;
    const int bc = zz & 3, sp = zz >> 2;
    const int b = bc >> 1, c = bc & 1;
    const int d0 = blockIdx.x * 128, n0 = blockIdx.y * 128;
    const int t = threadIdx.x;
    const int KS = NTOK / NSPLIT;                  // 1024

    if (t == 0) any = 0;
    __syncthreads();
    if (t < 128) {
        if (fsel[b * NTOK + n0 + t] == (float)c) any = 1;
    }
    __syncthreads();
    if (!any) return;

    f32x4 z = {0.f, 0.f, 0.f, 0.f};
    f32x4 acc[4][4];
#pragma unroll
    for (int i = 0; i < 4; ++i)
#pragma unroll
        for (int j = 0; j < 4; ++j) acc[i][j] = z;

    mm_core(Pbuf + ((size_t)bc * NTOK + n0) * NTOK + sp * KS, NTOK,
            yTb  + ((size_t)b  * D    + d0) * NTOK + sp * KS, NTOK,
            KS, As, Bs, acc);

    const int lane = t & 63, w = t >> 6;
    const int wr = w >> 1, wc = w & 1, l15 = lane & 15, l4 = lane >> 4;
    float* Os = Opart + (size_t)sp * BATCH * NTOK * D;
#pragma unroll
    for (int i = 0; i < 4; ++i)
#pragma unroll
        for (int e = 0; e < 4; ++e) {
            int n = n0 + wr * 64 + i * 16 + l4 * 4 + e;
            if (fsel[b * NTOK + n] == (float)c) {
                float* p = Os + ((size_t)b * NTOK + n) * D + d0 + wc * 64;
#pragma unroll
                for (int j = 0; j < 4; ++j) p[j * 16 + l15] = acc[i][j][e];
            }
        }
}

// ---------------------------------------------------------------------------
// Final: out = (cg/Zq * sum_s Opart + g*posY[ay]) / Srw
// ---------------------------------------------------------------------------
__global__ __launch_bounds__(256)
void k_final(const float* __restrict__ Opart, const float* __restrict__ posY,
             const float* __restrict__ Zq, const float* __restrict__ srw,
             const float* __restrict__ fsel, const float* __restrict__ gatingp,
             float* __restrict__ out) {
    int id = blockIdx.x * 256 + threadIdx.x;      // element-quads of [B,N,D]
    int e4 = id * 4;
    int d  = e4 & 255;
    int n  = (e4 >> 8) & 4095;
    int b  = e4 >> 20;
    const float g  = 1.f / (1.f + __expf(-gatingp[0]));
    const float cg = 1.f - g;
    int sel = (int)fsel[b * NTOK + n];
    int bc  = b * 2 + sel;
    float wq   = cg / Zq[bc * NTOK + n];
    float sinv = 1.f / srw[bc * NTOK + n];
    float4 o = make_float4(0.f, 0.f, 0.f, 0.f);
#pragma unroll
    for (int s = 0; s < NSPLIT; ++s) {
        float4 p = *(const float4*)&Opart[(size_t)s * BATCH * NTOK * D + e4];
        o.x += p.x; o.y += p.y; o.z += p.z; o.w += p.w;
    }
    float4 py = *(const float4*)&posY[((size_t)b * 64 + (n >> 6)) * D + d];
    float4 r;
    r.x = (o.x * wq + py.x * g) * sinv;
    r.y = (o.y * wq + py.y * g) * sinv;
    r.z = (o.z * wq + py.z * g) * sinv;
    r.w = (o.w * wq + py.w * g) * sinv;
    *(float4*)&out[e4] = r;
}

// ---------------------------------------------------------------------------
extern "C" void kernel_launch(void* const* d_in, const int* in_sizes, int n_in,
                              void* d_out, int out_size, void* d_ws, size_t ws_size,
                              hipStream_t stream) {
    const float* x      = (const float*)d_in[0];
    const float* y      = (const float*)d_in[1];
    const float* U      = (const float*)d_in[2];
    const float* S1     = (const float*)d_in[3];
    const float* S2     = (const float*)d_in[4];
    const float* focus  = (const float*)d_in[5];
    const float* gating = (const float*)d_in[6];
    const float* temp   = (const float*)d_in[7];
    float* out = (float*)d_out;

    char* p = (char*)d_ws;
    ushortt* M2b  = (ushortt*)p; p += (size_t)2 * D * D * 2;
    ushortt* xb   = (ushortt*)p; p += (size_t)BATCH * NTOK * D * 2;
    ushortt* yb   = (ushortt*)p; p += (size_t)BATCH * NTOK * D * 2;
    ushortt* yTb  = (ushortt*)p; p += (size_t)BATCH * D * NTOK * 2;
    ushortt* xsb  = (ushortt*)p; p += (size_t)NBC * NTOK * D * 2;
    float*   Ysum = (float*)p;   p += (size_t)BATCH * 64 * D * 4;
    float*   posY = (float*)p;   p += (size_t)BATCH * 64 * D * 4;
    float*   Zqp  = (float*)p;   p += (size_t)64 * NBC * NTOK * 4;
    float*   Zq   = (float*)p;   p += (size_t)NBC * NTOK * 4;
    float*   srw  = (float*)p;   p += (size_t)NBC * NTOK * 4;
    float*   ent  = (float*)p;   p += (size_t)NBC * NTOK * 4;
    float*   fsel = (float*)p;   p += (size_t)BATCH * NTOK * 4;
    float*   Opart= (float*)p;   p += (size_t)NSPLIT * BATCH * NTOK * D * 4;
    ushortt* Pbuf = (ushortt*)p; // NBC*NTOK*NTOK*2 = 134 MB

    k_prepM <<<512, 256, 0, stream>>>(U, S1, S2, M2b);
    k_cast  <<<2048, 256, 0, stream>>>(x, y, xb, yb);
    k_transT<<<dim3(64, 4, 2), 256, 0, stream>>>(y, yTb);
    k_ysum  <<<BATCH * 64, 256, 0, stream>>>(y, Ysum);
    k_posY  <<<BATCH * 64, 256, 0, stream>>>(Ysum, focus, posY);
    k_xs_mm <<<dim3(D / 128, NTOK / 128, NBC), 256, 0, stream>>>(xb, M2b, xsb);
    k_qkexp <<<dim3(NTOK / 128, NTOK / 128, NBC), 256, 0, stream>>>(xsb, yb, Pbuf, Zqp);
    k_zqred <<<NBC * NTOK / 256, 256, 0, stream>>>(Zqp, Zq);
    k_ent   <<<dim3(NTOK, NBC), 256, 0, stream>>>(Pbuf, Zq, focus, gating, ent, srw);
    k_route <<<BATCH * NTOK / 256, 256, 0, stream>>>(ent, temp, fsel, out);
    k_av_mm <<<dim3(D / 128, NTOK / 128, NBC * NSPLIT), 256, 0, stream>>>(Pbuf, yTb, fsel, Opart);
    k_final <<<BATCH * NTOK * D / 1024, 256, 0, stream>>>(Opart, posY, Zq, srw, fsel, gating, out);
}